// Round 1
// baseline (474.608 us; speedup 1.0000x reference)
//
#include <hip/hip_runtime.h>
#include <hip/hip_bf16.h>
#include <stdint.h>

// BitNet-style quantized FFN for MI355X (gfx950).
// Pipeline: absmax(w1,w2) -> scales -> wquant -> LN+actquant ->
//           i8 GEMM1 (+dequant+bias+swish, bf16 out) -> actquant(h) ->
//           i8 GEMM2 (+dequant+bias+mask+residual, fp32 out)

typedef int v4i __attribute__((ext_vector_type(4)));

#define BM 128
#define BN 128
#define BK 64
#define LDSS 80   // LDS row stride in bytes (64 data + 16 pad -> 2-way bank alias, free)

__device__ __forceinline__ float wave_max64(float v) {
#pragma unroll
  for (int off = 32; off; off >>= 1) v = fmaxf(v, __shfl_xor(v, off, 64));
  return v;
}

// ---------------- per-tensor weight absmax (atomicMax on float bits; poison is negative int) ----
__global__ __launch_bounds__(256) void absmax_kernel(const float* __restrict__ w, int n4,
                                                     int* __restrict__ slot) {
  float m = 0.f;
  const float4* w4 = (const float4*)w;
  for (int i = blockIdx.x * 256 + threadIdx.x; i < n4; i += gridDim.x * 256) {
    float4 v = w4[i];
    m = fmaxf(fmaxf(fabsf(v.x), fabsf(v.y)), fmaxf(fmaxf(fabsf(v.z), fabsf(v.w)), m));
  }
  m = wave_max64(m);
  __shared__ float sm[4];
  int lane = threadIdx.x & 63, wv = threadIdx.x >> 6;
  if (!lane) sm[wv] = m;
  __syncthreads();
  if (!threadIdx.x) {
    m = fmaxf(fmaxf(sm[0], sm[1]), fmaxf(sm[2], sm[3]));
    atomicMax(slot, __float_as_int(m));  // nonneg float bits are int-monotone
  }
}

// ---------------- scales: sw = qb/max(absmax,eps); reads bitwidth on device ----------------
__global__ void scales_kernel(const int* __restrict__ wmax, const int* __restrict__ bits,
                              float* __restrict__ scal) {
  float qb = (float)((1 << (bits[0] - 1)) - 1);
  scal[2] = qb / fmaxf(__int_as_float(wmax[0]), 1e-5f);
  scal[3] = qb / fmaxf(__int_as_float(wmax[1]), 1e-5f);
  scal[4] = qb;
}

// ---------------- weight quantization to int8 ----------------
__global__ __launch_bounds__(256) void wquant_kernel(const float* __restrict__ w,
                                                     const float* __restrict__ scal, int which,
                                                     int8_t* __restrict__ out) {
  float s = scal[2 + which], qb = scal[4];
  int i = blockIdx.x * 256 + threadIdx.x;
  float4 v = ((const float4*)w)[i];
  char4 q;
  q.x = (char)(int)rintf(fminf(fmaxf(v.x * s, -qb), qb));
  q.y = (char)(int)rintf(fminf(fmaxf(v.y * s, -qb), qb));
  q.z = (char)(int)rintf(fminf(fmaxf(v.z * s, -qb), qb));
  q.w = (char)(int)rintf(fminf(fmaxf(v.w * s, -qb), qb));
  ((char4*)out)[i] = q;
}

// ---------------- fused LayerNorm + per-row int8 absmax quant ----------------
__global__ __launch_bounds__(256) void ln_quant_kernel(const float* __restrict__ x,
                                                       const float* __restrict__ gamma,
                                                       const float* __restrict__ beta,
                                                       int8_t* __restrict__ xq,
                                                       float* __restrict__ xscale) {
  const int row = blockIdx.x;            // 16384 rows, D=1024
  const int tid = threadIdx.x;           // 256 threads x 4 elems
  const float4 v = ((const float4*)(x + (size_t)row * 1024))[tid];
  float s = v.x + v.y + v.z + v.w;
  float ss = fmaf(v.x, v.x, fmaf(v.y, v.y, fmaf(v.z, v.z, v.w * v.w)));
#pragma unroll
  for (int off = 32; off; off >>= 1) {
    s += __shfl_xor(s, off, 64);
    ss += __shfl_xor(ss, off, 64);
  }
  __shared__ float sm[8];
  const int lane = tid & 63, wv = tid >> 6;
  if (!lane) { sm[wv] = s; sm[4 + wv] = ss; }
  __syncthreads();
  s = sm[0] + sm[1] + sm[2] + sm[3];
  ss = sm[4] + sm[5] + sm[6] + sm[7];
  const float mu = s * (1.f / 1024.f);
  const float var = ss * (1.f / 1024.f) - mu * mu;
  const float rstd = rsqrtf(var + 1e-5f);
  const float4 g = ((const float4*)gamma)[tid];
  const float4 bb = ((const float4*)beta)[tid];
  float y0 = (v.x - mu) * rstd * g.x + bb.x;
  float y1 = (v.y - mu) * rstd * g.y + bb.y;
  float y2 = (v.z - mu) * rstd * g.z + bb.z;
  float y3 = (v.w - mu) * rstd * g.w + bb.w;
  float am = fmaxf(fmaxf(fabsf(y0), fabsf(y1)), fmaxf(fabsf(y2), fabsf(y3)));
  am = wave_max64(am);
  __syncthreads();
  if (!lane) sm[wv] = am;
  __syncthreads();
  am = fmaxf(fmaxf(sm[0], sm[1]), fmaxf(sm[2], sm[3]));
  const float scale = 127.f / fmaxf(am, 1e-5f);
  char4 q;
  q.x = (char)(int)rintf(fminf(fmaxf(y0 * scale, -127.f), 127.f));
  q.y = (char)(int)rintf(fminf(fmaxf(y1 * scale, -127.f), 127.f));
  q.z = (char)(int)rintf(fminf(fmaxf(y2 * scale, -127.f), 127.f));
  q.w = (char)(int)rintf(fminf(fmaxf(y3 * scale, -127.f), 127.f));
  ((char4*)(xq + (size_t)row * 1024))[tid] = q;
  if (!tid) xscale[row] = scale;
}

// ---------------- per-row int8 absmax quant of bf16 h [16384,4096] ----------------
__global__ __launch_bounds__(256) void hquant_kernel(const ushort* __restrict__ h,
                                                     int8_t* __restrict__ hq,
                                                     float* __restrict__ hscale) {
  const int row = blockIdx.x;
  const int tid = threadIdx.x;           // 256 threads x 16 elems
  const int4* p = (const int4*)(h + (size_t)row * 4096);
  union { int4 i4; ushort u[8]; } ua, ub;
  ua.i4 = p[tid * 2];
  ub.i4 = p[tid * 2 + 1];
  float f[16];
#pragma unroll
  for (int i = 0; i < 8; ++i) f[i] = __uint_as_float((unsigned)ua.u[i] << 16);
#pragma unroll
  for (int i = 0; i < 8; ++i) f[8 + i] = __uint_as_float((unsigned)ub.u[i] << 16);
  float am = 0.f;
#pragma unroll
  for (int i = 0; i < 16; ++i) am = fmaxf(am, fabsf(f[i]));
  am = wave_max64(am);
  __shared__ float sm[4];
  const int lane = tid & 63, wv = tid >> 6;
  if (!lane) sm[wv] = am;
  __syncthreads();
  am = fmaxf(fmaxf(sm[0], sm[1]), fmaxf(sm[2], sm[3]));
  const float scale = 127.f / fmaxf(am, 1e-5f);
  union { int4 i4; char c[16]; } q;
#pragma unroll
  for (int i = 0; i < 16; ++i)
    q.c[i] = (char)(int)rintf(fminf(fmaxf(f[i] * scale, -127.f), 127.f));
  ((int4*)(hq + (size_t)row * 4096))[tid] = q.i4;
  if (!tid) hscale[row] = scale;
}

// ---------------- i8 MFMA GEMM core: 128x128 tile, BK=64, 4 waves of 64x64 ----------------
template <int K>
__device__ __forceinline__ void gemm_core(const int8_t* __restrict__ A,
                                          const int8_t* __restrict__ B, int8_t* As, int8_t* Bs,
                                          v4i acc[4][4]) {
  const int tid = threadIdx.x;
  const int lane = tid & 63;
  const int wave = tid >> 6;
  const int wm = (wave & 1) << 6;
  const int wn = (wave >> 1) << 6;
  const int lrow = lane & 15;
  const int qk = (lane >> 4) << 4;        // k-offset of this lane's 16-byte chunk
  const size_t m0 = (size_t)blockIdx.y * BM;
  const size_t n0 = (size_t)blockIdx.x * BN;
  const int r0 = tid >> 2;                // staging rows 0..63
  const int r1 = r0 + 64;                 // staging rows 64..127
  const int c0 = (tid & 3) << 4;          // staging col offset {0,16,32,48}

  for (int k0 = 0; k0 < K; k0 += BK) {
    __syncthreads();
    v4i a0 = *(const v4i*)(A + (m0 + r0) * K + k0 + c0);
    v4i a1 = *(const v4i*)(A + (m0 + r1) * K + k0 + c0);
    v4i b0 = *(const v4i*)(B + (n0 + r0) * K + k0 + c0);
    v4i b1 = *(const v4i*)(B + (n0 + r1) * K + k0 + c0);
    *(v4i*)(As + r0 * LDSS + c0) = a0;
    *(v4i*)(As + r1 * LDSS + c0) = a1;
    *(v4i*)(Bs + r0 * LDSS + c0) = b0;
    *(v4i*)(Bs + r1 * LDSS + c0) = b1;
    __syncthreads();
    v4i af[4], bf[4];
#pragma unroll
    for (int i = 0; i < 4; ++i)
      af[i] = *(const v4i*)(As + (wm + i * 16 + lrow) * LDSS + qk);
#pragma unroll
    for (int j = 0; j < 4; ++j)
      bf[j] = *(const v4i*)(Bs + (wn + j * 16 + lrow) * LDSS + qk);
#pragma unroll
    for (int i = 0; i < 4; ++i)
#pragma unroll
      for (int j = 0; j < 4; ++j)
        acc[i][j] = __builtin_amdgcn_mfma_i32_16x16x64_i8(af[i], bf[j], acc[i][j], 0, 0, 0);
  }
}

// ---------------- GEMM1: C=xq@w1q^T, dequant+bias+swish -> bf16 h ----------------
__global__ __launch_bounds__(256) void gemm1_kernel(const int8_t* __restrict__ Aq,
                                                    const int8_t* __restrict__ Bq,
                                                    const float* __restrict__ xscale,
                                                    const float* __restrict__ scal,
                                                    const float* __restrict__ bias,
                                                    ushort* __restrict__ H) {
  __shared__ __align__(16) int8_t As[BM * LDSS];
  __shared__ __align__(16) int8_t Bs[BN * LDSS];
  v4i acc[4][4] = {};
  gemm_core<1024>(Aq, Bq, As, Bs, acc);
  const float sw1 = scal[2];
  const int lane = threadIdx.x & 63;
  const int wave = threadIdx.x >> 6;
  const int m0 = blockIdx.y * BM + ((wave & 1) << 6);
  const int n0 = blockIdx.x * BN + ((wave >> 1) << 6);
  const int ln = lane & 15, lq = lane >> 4;
#pragma unroll
  for (int i = 0; i < 4; ++i) {
#pragma unroll
    for (int r = 0; r < 4; ++r) {
      const int m = m0 + i * 16 + lq * 4 + r;
      const float rcp = 1.0f / (xscale[m] * sw1);
#pragma unroll
      for (int j = 0; j < 4; ++j) {
        const int n = n0 + j * 16 + ln;
        const float v = (float)acc[i][j][r] * rcp + bias[n];
        const float hsw = v / (1.0f + __expf(-v));  // swish
        __hip_bfloat16 hb = __float2bfloat16(hsw);
        H[(size_t)m * 4096 + n] = *(const ushort*)&hb;
      }
    }
  }
}

// ---------------- GEMM2: C=hq@w2q^T, dequant+bias+mask+residual -> fp32 out ----------------
__global__ __launch_bounds__(256) void gemm2_kernel(const int8_t* __restrict__ Aq,
                                                    const int8_t* __restrict__ Bq,
                                                    const float* __restrict__ hscale,
                                                    const float* __restrict__ scal,
                                                    const float* __restrict__ bias,
                                                    const float* __restrict__ x,
                                                    const float* __restrict__ mask,
                                                    float* __restrict__ out) {
  __shared__ __align__(16) int8_t As[BM * LDSS];
  __shared__ __align__(16) int8_t Bs[BN * LDSS];
  v4i acc[4][4] = {};
  gemm_core<4096>(Aq, Bq, As, Bs, acc);
  const float sw2 = scal[3];
  const int lane = threadIdx.x & 63;
  const int wave = threadIdx.x >> 6;
  const int m0 = blockIdx.y * BM + ((wave & 1) << 6);
  const int n0 = blockIdx.x * BN + ((wave >> 1) << 6);
  const int ln = lane & 15, lq = lane >> 4;
#pragma unroll
  for (int i = 0; i < 4; ++i) {
#pragma unroll
    for (int r = 0; r < 4; ++r) {
      const int m = m0 + i * 16 + lq * 4 + r;
      const float rcp = 1.0f / (hscale[m] * sw2);
      const float mk = 0.5f * mask[m];
#pragma unroll
      for (int j = 0; j < 4; ++j) {
        const int n = n0 + j * 16 + ln;
        const float v = (float)acc[i][j][r] * rcp + bias[n];
        const size_t idx = (size_t)m * 1024 + n;
        out[idx] = x[idx] + mk * v;
      }
    }
  }
}

extern "C" void kernel_launch(void* const* d_in, const int* in_sizes, int n_in, void* d_out,
                              int out_size, void* d_ws, size_t ws_size, hipStream_t stream) {
  const float* x = (const float*)d_in[0];      // [8,2048,1024]
  const float* mask = (const float*)d_in[1];   // [8,2048,1]
  const float* gamma = (const float*)d_in[2];  // [1024]
  const float* beta = (const float*)d_in[3];   // [1024]
  const float* w1 = (const float*)d_in[4];     // [4096,1024]
  const float* b1 = (const float*)d_in[5];     // [4096]
  const float* w2 = (const float*)d_in[6];     // [1024,4096]
  const float* b2 = (const float*)d_in[7];     // [1024]
  const int* bits = (const int*)d_in[8];       // scalar
  float* out = (float*)d_out;

  char* ws = (char*)d_ws;
  int* wmax = (int*)ws;                              // slots [0],[1]
  float* scal = (float*)ws;                          // [2]=sw1 [3]=sw2 [4]=qb
  float* xscale = (float*)(ws + (1u << 20));         // 16384 f32
  float* hscale = (float*)(ws + (2u << 20));         // 16384 f32
  int8_t* w1q = (int8_t*)(ws + (4u << 20));          // 4 MB
  int8_t* w2q = (int8_t*)(ws + (8u << 20));          // 4 MB
  int8_t* xq = (int8_t*)(ws + (12u << 20));          // 16 MB
  int8_t* hq = (int8_t*)(ws + (28u << 20));          // 64 MB
  ushort* h = (ushort*)(ws + (size_t)(92u << 20));   // 128 MB bf16

  const int NW = 4096 * 1024;  // elements per weight matrix

  absmax_kernel<<<1024, 256, 0, stream>>>(w1, NW / 4, wmax + 0);
  absmax_kernel<<<1024, 256, 0, stream>>>(w2, NW / 4, wmax + 1);
  scales_kernel<<<1, 1, 0, stream>>>(wmax, bits, scal);
  wquant_kernel<<<NW / 1024, 256, 0, stream>>>(w1, scal, 0, w1q);
  wquant_kernel<<<NW / 1024, 256, 0, stream>>>(w2, scal, 1, w2q);
  ln_quant_kernel<<<16384, 256, 0, stream>>>(x, gamma, beta, xq, xscale);
  gemm1_kernel<<<dim3(4096 / BN, 16384 / BM), 256, 0, stream>>>(xq, w1q, xscale, scal, b1, h);
  hquant_kernel<<<16384, 256, 0, stream>>>(h, hq, hscale);
  gemm2_kernel<<<dim3(1024 / BN, 16384 / BM), 256, 0, stream>>>(hq, w2q, hscale, scal, b2, x,
                                                                mask, out);
}

// Round 2
// 465.167 us; speedup vs baseline: 1.0203x; 1.0203x over previous
//
#include <hip/hip_runtime.h>
#include <hip/hip_bf16.h>
#include <stdint.h>

// BitNet-style quantized FFN for MI355X (gfx950).
// Pipeline: absmax(w1,w2) -> scales -> wquant -> LN+actquant ->
//           i8 GEMM1 (+dequant+bias+swish, bf16 out) -> actquant(h) ->
//           i8 GEMM2 (+dequant+bias+mask+residual, fp32 out)
// R2: GEMM staging via global_load_lds width=16 (m97 ladder rung), packed
//     64-B LDS rows (global_load_lds needs wave-uniform base + lane*16).

typedef int v4i __attribute__((ext_vector_type(4)));

#define BM 128
#define BN 128
#define BK 64

__device__ __forceinline__ float wave_max64(float v) {
#pragma unroll
  for (int off = 32; off; off >>= 1) v = fmaxf(v, __shfl_xor(v, off, 64));
  return v;
}

__device__ __forceinline__ void load16_to_lds(const int8_t* g, int8_t* l) {
  __builtin_amdgcn_global_load_lds((const __attribute__((address_space(1))) void*)g,
                                   (__attribute__((address_space(3))) void*)l, 16, 0, 0);
}

// ---------------- per-tensor weight absmax ----------------
__global__ __launch_bounds__(256) void absmax_kernel(const float* __restrict__ w, int n4,
                                                     int* __restrict__ slot) {
  float m = 0.f;
  const float4* w4 = (const float4*)w;
  for (int i = blockIdx.x * 256 + threadIdx.x; i < n4; i += gridDim.x * 256) {
    float4 v = w4[i];
    m = fmaxf(fmaxf(fabsf(v.x), fabsf(v.y)), fmaxf(fmaxf(fabsf(v.z), fabsf(v.w)), m));
  }
  m = wave_max64(m);
  __shared__ float sm[4];
  int lane = threadIdx.x & 63, wv = threadIdx.x >> 6;
  if (!lane) sm[wv] = m;
  __syncthreads();
  if (!threadIdx.x) {
    m = fmaxf(fmaxf(sm[0], sm[1]), fmaxf(sm[2], sm[3]));
    atomicMax(slot, __float_as_int(m));  // nonneg float bits are int-monotone
  }
}

// ---------------- scales ----------------
__global__ void scales_kernel(const int* __restrict__ wmax, const int* __restrict__ bits,
                              float* __restrict__ scal) {
  float qb = (float)((1 << (bits[0] - 1)) - 1);
  scal[2] = qb / fmaxf(__int_as_float(wmax[0]), 1e-5f);
  scal[3] = qb / fmaxf(__int_as_float(wmax[1]), 1e-5f);
  scal[4] = qb;
}

// ---------------- weight quantization to int8 ----------------
__global__ __launch_bounds__(256) void wquant_kernel(const float* __restrict__ w,
                                                     const float* __restrict__ scal, int which,
                                                     int8_t* __restrict__ out) {
  float s = scal[2 + which], qb = scal[4];
  int i = blockIdx.x * 256 + threadIdx.x;
  float4 v = ((const float4*)w)[i];
  char4 q;
  q.x = (char)(int)rintf(fminf(fmaxf(v.x * s, -qb), qb));
  q.y = (char)(int)rintf(fminf(fmaxf(v.y * s, -qb), qb));
  q.z = (char)(int)rintf(fminf(fmaxf(v.z * s, -qb), qb));
  q.w = (char)(int)rintf(fminf(fmaxf(v.w * s, -qb), qb));
  ((char4*)out)[i] = q;
}

// ---------------- fused LayerNorm + per-row int8 absmax quant ----------------
__global__ __launch_bounds__(256) void ln_quant_kernel(const float* __restrict__ x,
                                                       const float* __restrict__ gamma,
                                                       const float* __restrict__ beta,
                                                       int8_t* __restrict__ xq,
                                                       float* __restrict__ xscale) {
  const int row = blockIdx.x;            // 16384 rows, D=1024
  const int tid = threadIdx.x;           // 256 threads x 4 elems
  const float4 v = ((const float4*)(x + (size_t)row * 1024))[tid];
  float s = v.x + v.y + v.z + v.w;
  float ss = fmaf(v.x, v.x, fmaf(v.y, v.y, fmaf(v.z, v.z, v.w * v.w)));
#pragma unroll
  for (int off = 32; off; off >>= 1) {
    s += __shfl_xor(s, off, 64);
    ss += __shfl_xor(ss, off, 64);
  }
  __shared__ float sm[8];
  const int lane = tid & 63, wv = tid >> 6;
  if (!lane) { sm[wv] = s; sm[4 + wv] = ss; }
  __syncthreads();
  s = sm[0] + sm[1] + sm[2] + sm[3];
  ss = sm[4] + sm[5] + sm[6] + sm[7];
  const float mu = s * (1.f / 1024.f);
  const float var = ss * (1.f / 1024.f) - mu * mu;
  const float rstd = rsqrtf(var + 1e-5f);
  const float4 g = ((const float4*)gamma)[tid];
  const float4 bb = ((const float4*)beta)[tid];
  float y0 = (v.x - mu) * rstd * g.x + bb.x;
  float y1 = (v.y - mu) * rstd * g.y + bb.y;
  float y2 = (v.z - mu) * rstd * g.z + bb.z;
  float y3 = (v.w - mu) * rstd * g.w + bb.w;
  float am = fmaxf(fmaxf(fabsf(y0), fabsf(y1)), fmaxf(fabsf(y2), fabsf(y3)));
  am = wave_max64(am);
  __syncthreads();
  if (!lane) sm[wv] = am;
  __syncthreads();
  am = fmaxf(fmaxf(sm[0], sm[1]), fmaxf(sm[2], sm[3]));
  const float scale = 127.f / fmaxf(am, 1e-5f);
  char4 q;
  q.x = (char)(int)rintf(fminf(fmaxf(y0 * scale, -127.f), 127.f));
  q.y = (char)(int)rintf(fminf(fmaxf(y1 * scale, -127.f), 127.f));
  q.z = (char)(int)rintf(fminf(fmaxf(y2 * scale, -127.f), 127.f));
  q.w = (char)(int)rintf(fminf(fmaxf(y3 * scale, -127.f), 127.f));
  ((char4*)(xq + (size_t)row * 1024))[tid] = q;
  if (!tid) xscale[row] = scale;
}

// ---------------- per-row int8 absmax quant of bf16 h [16384,4096] ----------------
__global__ __launch_bounds__(256) void hquant_kernel(const ushort* __restrict__ h,
                                                     int8_t* __restrict__ hq,
                                                     float* __restrict__ hscale) {
  const int row = blockIdx.x;
  const int tid = threadIdx.x;           // 256 threads x 16 elems
  const int4* p = (const int4*)(h + (size_t)row * 4096);
  union { int4 i4; ushort u[8]; } ua, ub;
  ua.i4 = p[tid * 2];
  ub.i4 = p[tid * 2 + 1];
  float f[16];
#pragma unroll
  for (int i = 0; i < 8; ++i) f[i] = __uint_as_float((unsigned)ua.u[i] << 16);
#pragma unroll
  for (int i = 0; i < 8; ++i) f[8 + i] = __uint_as_float((unsigned)ub.u[i] << 16);
  float am = 0.f;
#pragma unroll
  for (int i = 0; i < 16; ++i) am = fmaxf(am, fabsf(f[i]));
  am = wave_max64(am);
  __shared__ float sm[4];
  const int lane = tid & 63, wv = tid >> 6;
  if (!lane) sm[wv] = am;
  __syncthreads();
  am = fmaxf(fmaxf(sm[0], sm[1]), fmaxf(sm[2], sm[3]));
  const float scale = 127.f / fmaxf(am, 1e-5f);
  union { int4 i4; char c[16]; } q;
#pragma unroll
  for (int i = 0; i < 16; ++i)
    q.c[i] = (char)(int)rintf(fminf(fmaxf(f[i] * scale, -127.f), 127.f));
  ((int4*)(hq + (size_t)row * 4096))[tid] = q.i4;
  if (!tid) hscale[row] = scale;
}

// ---------------- i8 MFMA GEMM core: 128x128 tile, BK=64, 4 waves of 64x64 ----
// Staging via global_load_lds width=16: lane `tid` of wave w targets LDS
// offset tid*16 = w*1024 + lane*16 -> wave-uniform base + lane*16 (required).
// LDS rows packed at 64 B (no padding allowed with global_load_lds).
template <int K>
__device__ __forceinline__ void gemm_core(const int8_t* __restrict__ A,
                                          const int8_t* __restrict__ B, int8_t* As, int8_t* Bs,
                                          v4i acc[4][4]) {
  const int tid = threadIdx.x;
  const int lane = tid & 63;
  const int wave = tid >> 6;
  const int wm = (wave & 1) << 6;
  const int wn = (wave >> 1) << 6;
  const int lrow = lane & 15;
  const int qk = (lane >> 4) << 4;        // k-byte offset of this lane's 16-byte chunk
  const size_t m0 = (size_t)blockIdx.y * BM;
  const size_t n0 = (size_t)blockIdx.x * BN;
  const int r0 = tid >> 2;                // staging rows 0..63 (segment 0)
  const int c0 = (tid & 3) << 4;          // staging col offset {0,16,32,48}

  const int8_t* ga0 = A + (m0 + r0) * K + c0;
  const int8_t* ga1 = A + (m0 + 64 + r0) * K + c0;
  const int8_t* gb0 = B + (n0 + r0) * K + c0;
  const int8_t* gb1 = B + (n0 + 64 + r0) * K + c0;
  int8_t* la0 = As + tid * 16;
  int8_t* la1 = As + 4096 + tid * 16;
  int8_t* lb0 = Bs + tid * 16;
  int8_t* lb1 = Bs + 4096 + tid * 16;

  for (int k0 = 0; k0 < K; k0 += BK) {
    __syncthreads();                       // prev tile's ds_reads complete
    load16_to_lds(ga0 + k0, la0);
    load16_to_lds(ga1 + k0, la1);
    load16_to_lds(gb0 + k0, lb0);
    load16_to_lds(gb1 + k0, lb1);
    __syncthreads();                       // drains vmcnt: staging visible
    v4i af[4], bf[4];
#pragma unroll
    for (int i = 0; i < 4; ++i)
      af[i] = *(const v4i*)(As + (wm + i * 16 + lrow) * 64 + qk);
#pragma unroll
    for (int j = 0; j < 4; ++j)
      bf[j] = *(const v4i*)(Bs + (wn + j * 16 + lrow) * 64 + qk);
#pragma unroll
    for (int i = 0; i < 4; ++i)
#pragma unroll
      for (int j = 0; j < 4; ++j)
        acc[i][j] = __builtin_amdgcn_mfma_i32_16x16x64_i8(af[i], bf[j], acc[i][j], 0, 0, 0);
  }
}

// ---------------- GEMM1: C=xq@w1q^T, dequant+bias+swish -> bf16 h ----------------
__global__ __launch_bounds__(256) void gemm1_kernel(const int8_t* __restrict__ Aq,
                                                    const int8_t* __restrict__ Bq,
                                                    const float* __restrict__ xscale,
                                                    const float* __restrict__ scal,
                                                    const float* __restrict__ bias,
                                                    ushort* __restrict__ H) {
  __shared__ __align__(16) int8_t As[BM * BK];
  __shared__ __align__(16) int8_t Bs[BN * BK];
  v4i acc[4][4] = {};
  gemm_core<1024>(Aq, Bq, As, Bs, acc);
  const float sw1 = scal[2];
  const int lane = threadIdx.x & 63;
  const int wave = threadIdx.x >> 6;
  const int m0 = blockIdx.y * BM + ((wave & 1) << 6);
  const int n0 = blockIdx.x * BN + ((wave >> 1) << 6);
  const int ln = lane & 15, lq = lane >> 4;
#pragma unroll
  for (int i = 0; i < 4; ++i) {
#pragma unroll
    for (int r = 0; r < 4; ++r) {
      const int m = m0 + i * 16 + lq * 4 + r;
      const float rcp = 1.0f / (xscale[m] * sw1);
#pragma unroll
      for (int j = 0; j < 4; ++j) {
        const int n = n0 + j * 16 + ln;
        const float v = (float)acc[i][j][r] * rcp + bias[n];
        const float hsw = v / (1.0f + __expf(-v));  // swish
        __hip_bfloat16 hb = __float2bfloat16(hsw);
        H[(size_t)m * 4096 + n] = *(const ushort*)&hb;
      }
    }
  }
}

// ---------------- GEMM2: C=hq@w2q^T, dequant+bias+mask+residual -> fp32 out ----------------
__global__ __launch_bounds__(256) void gemm2_kernel(const int8_t* __restrict__ Aq,
                                                    const int8_t* __restrict__ Bq,
                                                    const float* __restrict__ hscale,
                                                    const float* __restrict__ scal,
                                                    const float* __restrict__ bias,
                                                    const float* __restrict__ x,
                                                    const float* __restrict__ mask,
                                                    float* __restrict__ out) {
  __shared__ __align__(16) int8_t As[BM * BK];
  __shared__ __align__(16) int8_t Bs[BN * BK];
  v4i acc[4][4] = {};
  gemm_core<4096>(Aq, Bq, As, Bs, acc);
  const float sw2 = scal[3];
  const int lane = threadIdx.x & 63;
  const int wave = threadIdx.x >> 6;
  const int m0 = blockIdx.y * BM + ((wave & 1) << 6);
  const int n0 = blockIdx.x * BN + ((wave >> 1) << 6);
  const int ln = lane & 15, lq = lane >> 4;
#pragma unroll
  for (int i = 0; i < 4; ++i) {
#pragma unroll
    for (int r = 0; r < 4; ++r) {
      const int m = m0 + i * 16 + lq * 4 + r;
      const float rcp = 1.0f / (hscale[m] * sw2);
      const float mk = 0.5f * mask[m];
#pragma unroll
      for (int j = 0; j < 4; ++j) {
        const int n = n0 + j * 16 + ln;
        const float v = (float)acc[i][j][r] * rcp + bias[n];
        const size_t idx = (size_t)m * 1024 + n;
        out[idx] = x[idx] + mk * v;
      }
    }
  }
}

extern "C" void kernel_launch(void* const* d_in, const int* in_sizes, int n_in, void* d_out,
                              int out_size, void* d_ws, size_t ws_size, hipStream_t stream) {
  const float* x = (const float*)d_in[0];      // [8,2048,1024]
  const float* mask = (const float*)d_in[1];   // [8,2048,1]
  const float* gamma = (const float*)d_in[2];  // [1024]
  const float* beta = (const float*)d_in[3];   // [1024]
  const float* w1 = (const float*)d_in[4];     // [4096,1024]
  const float* b1 = (const float*)d_in[5];     // [4096]
  const float* w2 = (const float*)d_in[6];     // [1024,4096]
  const float* b2 = (const float*)d_in[7];     // [1024]
  const int* bits = (const int*)d_in[8];       // scalar
  float* out = (float*)d_out;

  char* ws = (char*)d_ws;
  int* wmax = (int*)ws;                              // slots [0],[1]
  float* scal = (float*)ws;                          // [2]=sw1 [3]=sw2 [4]=qb
  float* xscale = (float*)(ws + (1u << 20));         // 16384 f32
  float* hscale = (float*)(ws + (2u << 20));         // 16384 f32
  int8_t* w1q = (int8_t*)(ws + (4u << 20));          // 4 MB
  int8_t* w2q = (int8_t*)(ws + (8u << 20));          // 4 MB
  int8_t* xq = (int8_t*)(ws + (12u << 20));          // 16 MB
  int8_t* hq = (int8_t*)(ws + (28u << 20));          // 64 MB
  ushort* h = (ushort*)(ws + (size_t)(92u << 20));   // 128 MB bf16

  const int NW = 4096 * 1024;  // elements per weight matrix

  absmax_kernel<<<1024, 256, 0, stream>>>(w1, NW / 4, wmax + 0);
  absmax_kernel<<<1024, 256, 0, stream>>>(w2, NW / 4, wmax + 1);
  scales_kernel<<<1, 1, 0, stream>>>(wmax, bits, scal);
  wquant_kernel<<<NW / 1024, 256, 0, stream>>>(w1, scal, 0, w1q);
  wquant_kernel<<<NW / 1024, 256, 0, stream>>>(w2, scal, 1, w2q);
  ln_quant_kernel<<<16384, 256, 0, stream>>>(x, gamma, beta, xq, xscale);
  gemm1_kernel<<<dim3(4096 / BN, 16384 / BM), 256, 0, stream>>>(xq, w1q, xscale, scal, b1, h);
  hquant_kernel<<<16384, 256, 0, stream>>>(h, hq, hscale);
  gemm2_kernel<<<dim3(1024 / BN, 16384 / BM), 256, 0, stream>>>(hq, w2q, hscale, scal, b2, x,
                                                                mask, out);
}

// Round 3
// 441.333 us; speedup vs baseline: 1.0754x; 1.0540x over previous
//
#include <hip/hip_runtime.h>
#include <hip/hip_bf16.h>
#include <stdint.h>

// BitNet-style quantized FFN for MI355X (gfx950).
// Pipeline: absmax(w1,w2) -> scales -> wquant -> LN+actquant ->
//           i8 GEMM1 (+dequant+bias+swish, bf16 out) -> actquant(h) ->
//           i8 GEMM2 (+dequant+bias+mask+residual, fp32 out)
// R3: GEMM core rewrite: 32x32x32 i8 MFMA (higher ceiling, half the issue
//     slots), BK=128 (half the barriers, 32KB LDS), XOR bank-swizzle done at
//     global-fetch time (global_load_lds fixes LDS dest = base+lane*16, but
//     the per-lane GLOBAL address is free — so permute k-segments there).

typedef int v4i __attribute__((ext_vector_type(4)));
typedef int v16i __attribute__((ext_vector_type(16)));

#define BM 128
#define BN 128
#define BK 128   // bytes (=i8 elems) of K per tile

__device__ __forceinline__ float wave_max64(float v) {
#pragma unroll
  for (int off = 32; off; off >>= 1) v = fmaxf(v, __shfl_xor(v, off, 64));
  return v;
}

__device__ __forceinline__ void load16_to_lds(const int8_t* g, int8_t* l) {
  __builtin_amdgcn_global_load_lds((const __attribute__((address_space(1))) void*)g,
                                   (__attribute__((address_space(3))) void*)l, 16, 0, 0);
}

// ---------------- per-tensor weight absmax ----------------
__global__ __launch_bounds__(256) void absmax_kernel(const float* __restrict__ w, int n4,
                                                     int* __restrict__ slot) {
  float m = 0.f;
  const float4* w4 = (const float4*)w;
  for (int i = blockIdx.x * 256 + threadIdx.x; i < n4; i += gridDim.x * 256) {
    float4 v = w4[i];
    m = fmaxf(fmaxf(fabsf(v.x), fabsf(v.y)), fmaxf(fmaxf(fabsf(v.z), fabsf(v.w)), m));
  }
  m = wave_max64(m);
  __shared__ float sm[4];
  int lane = threadIdx.x & 63, wv = threadIdx.x >> 6;
  if (!lane) sm[wv] = m;
  __syncthreads();
  if (!threadIdx.x) {
    m = fmaxf(fmaxf(sm[0], sm[1]), fmaxf(sm[2], sm[3]));
    atomicMax(slot, __float_as_int(m));  // nonneg float bits are int-monotone
  }
}

// ---------------- scales ----------------
__global__ void scales_kernel(const int* __restrict__ wmax, const int* __restrict__ bits,
                              float* __restrict__ scal) {
  float qb = (float)((1 << (bits[0] - 1)) - 1);
  scal[2] = qb / fmaxf(__int_as_float(wmax[0]), 1e-5f);
  scal[3] = qb / fmaxf(__int_as_float(wmax[1]), 1e-5f);
  scal[4] = qb;
}

// ---------------- weight quantization to int8 ----------------
__global__ __launch_bounds__(256) void wquant_kernel(const float* __restrict__ w,
                                                     const float* __restrict__ scal, int which,
                                                     int8_t* __restrict__ out) {
  float s = scal[2 + which], qb = scal[4];
  int i = blockIdx.x * 256 + threadIdx.x;
  float4 v = ((const float4*)w)[i];
  char4 q;
  q.x = (char)(int)rintf(fminf(fmaxf(v.x * s, -qb), qb));
  q.y = (char)(int)rintf(fminf(fmaxf(v.y * s, -qb), qb));
  q.z = (char)(int)rintf(fminf(fmaxf(v.z * s, -qb), qb));
  q.w = (char)(int)rintf(fminf(fmaxf(v.w * s, -qb), qb));
  ((char4*)out)[i] = q;
}

// ---------------- fused LayerNorm + per-row int8 absmax quant ----------------
__global__ __launch_bounds__(256) void ln_quant_kernel(const float* __restrict__ x,
                                                       const float* __restrict__ gamma,
                                                       const float* __restrict__ beta,
                                                       int8_t* __restrict__ xq,
                                                       float* __restrict__ xscale) {
  const int row = blockIdx.x;            // 16384 rows, D=1024
  const int tid = threadIdx.x;           // 256 threads x 4 elems
  const float4 v = ((const float4*)(x + (size_t)row * 1024))[tid];
  float s = v.x + v.y + v.z + v.w;
  float ss = fmaf(v.x, v.x, fmaf(v.y, v.y, fmaf(v.z, v.z, v.w * v.w)));
#pragma unroll
  for (int off = 32; off; off >>= 1) {
    s += __shfl_xor(s, off, 64);
    ss += __shfl_xor(ss, off, 64);
  }
  __shared__ float sm[8];
  const int lane = tid & 63, wv = tid >> 6;
  if (!lane) { sm[wv] = s; sm[4 + wv] = ss; }
  __syncthreads();
  s = sm[0] + sm[1] + sm[2] + sm[3];
  ss = sm[4] + sm[5] + sm[6] + sm[7];
  const float mu = s * (1.f / 1024.f);
  const float var = ss * (1.f / 1024.f) - mu * mu;
  const float rstd = rsqrtf(var + 1e-5f);
  const float4 g = ((const float4*)gamma)[tid];
  const float4 bb = ((const float4*)beta)[tid];
  float y0 = (v.x - mu) * rstd * g.x + bb.x;
  float y1 = (v.y - mu) * rstd * g.y + bb.y;
  float y2 = (v.z - mu) * rstd * g.z + bb.z;
  float y3 = (v.w - mu) * rstd * g.w + bb.w;
  float am = fmaxf(fmaxf(fabsf(y0), fabsf(y1)), fmaxf(fabsf(y2), fabsf(y3)));
  am = wave_max64(am);
  __syncthreads();
  if (!lane) sm[wv] = am;
  __syncthreads();
  am = fmaxf(fmaxf(sm[0], sm[1]), fmaxf(sm[2], sm[3]));
  const float scale = 127.f / fmaxf(am, 1e-5f);
  char4 q;
  q.x = (char)(int)rintf(fminf(fmaxf(y0 * scale, -127.f), 127.f));
  q.y = (char)(int)rintf(fminf(fmaxf(y1 * scale, -127.f), 127.f));
  q.z = (char)(int)rintf(fminf(fmaxf(y2 * scale, -127.f), 127.f));
  q.w = (char)(int)rintf(fminf(fmaxf(y3 * scale, -127.f), 127.f));
  ((char4*)(xq + (size_t)row * 1024))[tid] = q;
  if (!tid) xscale[row] = scale;
}

// ---------------- per-row int8 absmax quant of bf16 h [16384,4096] ----------------
__global__ __launch_bounds__(256) void hquant_kernel(const ushort* __restrict__ h,
                                                     int8_t* __restrict__ hq,
                                                     float* __restrict__ hscale) {
  const int row = blockIdx.x;
  const int tid = threadIdx.x;           // 256 threads x 16 elems
  const int4* p = (const int4*)(h + (size_t)row * 4096);
  union { int4 i4; ushort u[8]; } ua, ub;
  ua.i4 = p[tid * 2];
  ub.i4 = p[tid * 2 + 1];
  float f[16];
#pragma unroll
  for (int i = 0; i < 8; ++i) f[i] = __uint_as_float((unsigned)ua.u[i] << 16);
#pragma unroll
  for (int i = 0; i < 8; ++i) f[8 + i] = __uint_as_float((unsigned)ub.u[i] << 16);
  float am = 0.f;
#pragma unroll
  for (int i = 0; i < 16; ++i) am = fmaxf(am, fabsf(f[i]));
  am = wave_max64(am);
  __shared__ float sm[4];
  const int lane = tid & 63, wv = tid >> 6;
  if (!lane) sm[wv] = am;
  __syncthreads();
  am = fmaxf(fmaxf(sm[0], sm[1]), fmaxf(sm[2], sm[3]));
  const float scale = 127.f / fmaxf(am, 1e-5f);
  union { int4 i4; char c[16]; } q;
#pragma unroll
  for (int i = 0; i < 16; ++i)
    q.c[i] = (char)(int)rintf(fminf(fmaxf(f[i] * scale, -127.f), 127.f));
  ((int4*)(hq + (size_t)row * 4096))[tid] = q.i4;
  if (!tid) hscale[row] = scale;
}

// ---------------- i8 MFMA GEMM core: 128x128 tile, BK=128, 32x32x32, 4 waves ----
// LDS tile: 128 rows x 128 B, physical slot (r, s) holds global k-chunk
// s ^ (r&7) of row r (XOR swizzle applied at global-fetch addressing, since
// global_load_lds requires LDS dest = wave-uniform base + lane*16).
// Fragment reads then hit all 8 bank-groups uniformly -> conflict-free.
template <int K>
__device__ __forceinline__ void gemm_core(const int8_t* __restrict__ A,
                                          const int8_t* __restrict__ B, int8_t* As, int8_t* Bs,
                                          v16i acc[2][2]) {
  const int tid = threadIdx.x;
  const int lane = tid & 63;
  const int wave = tid >> 6;
  const int wm = (wave & 1) << 6;
  const int wn = (wave >> 1) << 6;
  const int lrow = lane & 31;
  const int half = lane >> 5;            // k-half selector for 32x32x32 frags
  const size_t m0 = (size_t)blockIdx.y * BM;
  const size_t n0 = (size_t)blockIdx.x * BN;

  // staging: chunk index ci = wave*64+lane (+t*256); r=ci>>3, sphys=ci&7
  const int ci = wave * 64 + lane;
  const int rA = ci >> 3;                // row for t=0; t adds 32 (doesn't change r&7)
  const int cs = ((ci & 7) ^ (rA & 7)) << 4;  // swizzled global k-byte offset
  const int8_t* ga = A + (m0 + rA) * K + cs;
  const int8_t* gb = B + (n0 + rA) * K + cs;
  int8_t* la = As + ci * 16;
  int8_t* lb = Bs + ci * 16;
  const int x7 = (lrow & 7);

  for (int k0 = 0; k0 < K; k0 += BK) {
    __syncthreads();
#pragma unroll
    for (int t = 0; t < 4; ++t) {
      load16_to_lds(ga + (size_t)(t * 32) * K + k0, la + t * 4096);
      load16_to_lds(gb + (size_t)(t * 32) * K + k0, lb + t * 4096);
    }
    __syncthreads();
#pragma unroll
    for (int ks = 0; ks < 4; ++ks) {
      const int so = ((ks * 2 + half) ^ x7) << 4;  // swizzled segment offset
      v4i a0 = *(const v4i*)(As + (wm + lrow) * 128 + so);
      v4i a1 = *(const v4i*)(As + (wm + 32 + lrow) * 128 + so);
      v4i b0 = *(const v4i*)(Bs + (wn + lrow) * 128 + so);
      v4i b1 = *(const v4i*)(Bs + (wn + 32 + lrow) * 128 + so);
      acc[0][0] = __builtin_amdgcn_mfma_i32_32x32x32_i8(a0, b0, acc[0][0], 0, 0, 0);
      acc[0][1] = __builtin_amdgcn_mfma_i32_32x32x32_i8(a0, b1, acc[0][1], 0, 0, 0);
      acc[1][0] = __builtin_amdgcn_mfma_i32_32x32x32_i8(a1, b0, acc[1][0], 0, 0, 0);
      acc[1][1] = __builtin_amdgcn_mfma_i32_32x32x32_i8(a1, b1, acc[1][1], 0, 0, 0);
    }
  }
}

// ---------------- GEMM1: C=xq@w1q^T, dequant+bias+swish -> bf16 h ----------------
__global__ __launch_bounds__(256) void gemm1_kernel(const int8_t* __restrict__ Aq,
                                                    const int8_t* __restrict__ Bq,
                                                    const float* __restrict__ xscale,
                                                    const float* __restrict__ scal,
                                                    const float* __restrict__ bias,
                                                    ushort* __restrict__ H) {
  __shared__ __align__(16) int8_t As[BM * BK];
  __shared__ __align__(16) int8_t Bs[BN * BK];
  v16i acc[2][2] = {};
  gemm_core<1024>(Aq, Bq, As, Bs, acc);
  const float sw1 = scal[2];
  const int lane = threadIdx.x & 63;
  const int wave = threadIdx.x >> 6;
  const int m0 = blockIdx.y * BM + ((wave & 1) << 6);
  const int n0 = blockIdx.x * BN + ((wave >> 1) << 6);
  const int cn = lane & 31;
  const int h4 = (lane >> 5) << 2;
#pragma unroll
  for (int i = 0; i < 2; ++i) {
#pragma unroll
    for (int reg = 0; reg < 16; ++reg) {
      const int row = (reg & 3) + ((reg >> 2) << 3) + h4;  // C/D layout (m74/m101)
      const int m = m0 + i * 32 + row;
      const float rcp = 1.0f / (xscale[m] * sw1);
#pragma unroll
      for (int j = 0; j < 2; ++j) {
        const int n = n0 + j * 32 + cn;
        const float v = (float)acc[i][j][reg] * rcp + bias[n];
        const float hsw = v / (1.0f + __expf(-v));  // swish
        __hip_bfloat16 hb = __float2bfloat16(hsw);
        H[(size_t)m * 4096 + n] = *(const ushort*)&hb;
      }
    }
  }
}

// ---------------- GEMM2: C=hq@w2q^T, dequant+bias+mask+residual -> fp32 out ----------------
__global__ __launch_bounds__(256) void gemm2_kernel(const int8_t* __restrict__ Aq,
                                                    const int8_t* __restrict__ Bq,
                                                    const float* __restrict__ hscale,
                                                    const float* __restrict__ scal,
                                                    const float* __restrict__ bias,
                                                    const float* __restrict__ x,
                                                    const float* __restrict__ mask,
                                                    float* __restrict__ out) {
  __shared__ __align__(16) int8_t As[BM * BK];
  __shared__ __align__(16) int8_t Bs[BN * BK];
  v16i acc[2][2] = {};
  gemm_core<4096>(Aq, Bq, As, Bs, acc);
  const float sw2 = scal[3];
  const int lane = threadIdx.x & 63;
  const int wave = threadIdx.x >> 6;
  const int m0 = blockIdx.y * BM + ((wave & 1) << 6);
  const int n0 = blockIdx.x * BN + ((wave >> 1) << 6);
  const int cn = lane & 31;
  const int h4 = (lane >> 5) << 2;
#pragma unroll
  for (int i = 0; i < 2; ++i) {
#pragma unroll
    for (int reg = 0; reg < 16; ++reg) {
      const int row = (reg & 3) + ((reg >> 2) << 3) + h4;
      const int m = m0 + i * 32 + row;
      const float rcp = 1.0f / (hscale[m] * sw2);
      const float mk = 0.5f * mask[m];
#pragma unroll
      for (int j = 0; j < 2; ++j) {
        const int n = n0 + j * 32 + cn;
        const float v = (float)acc[i][j][reg] * rcp + bias[n];
        const size_t idx = (size_t)m * 1024 + n;
        out[idx] = x[idx] + mk * v;
      }
    }
  }
}

extern "C" void kernel_launch(void* const* d_in, const int* in_sizes, int n_in, void* d_out,
                              int out_size, void* d_ws, size_t ws_size, hipStream_t stream) {
  const float* x = (const float*)d_in[0];      // [8,2048,1024]
  const float* mask = (const float*)d_in[1];   // [8,2048,1]
  const float* gamma = (const float*)d_in[2];  // [1024]
  const float* beta = (const float*)d_in[3];   // [1024]
  const float* w1 = (const float*)d_in[4];     // [4096,1024]
  const float* b1 = (const float*)d_in[5];     // [4096]
  const float* w2 = (const float*)d_in[6];     // [1024,4096]
  const float* b2 = (const float*)d_in[7];     // [1024]
  const int* bits = (const int*)d_in[8];       // scalar
  float* out = (float*)d_out;

  char* ws = (char*)d_ws;
  int* wmax = (int*)ws;                              // slots [0],[1]
  float* scal = (float*)ws;                          // [2]=sw1 [3]=sw2 [4]=qb
  float* xscale = (float*)(ws + (1u << 20));         // 16384 f32
  float* hscale = (float*)(ws + (2u << 20));         // 16384 f32
  int8_t* w1q = (int8_t*)(ws + (4u << 20));          // 4 MB
  int8_t* w2q = (int8_t*)(ws + (8u << 20));          // 4 MB
  int8_t* xq = (int8_t*)(ws + (12u << 20));          // 16 MB
  int8_t* hq = (int8_t*)(ws + (28u << 20));          // 64 MB
  ushort* h = (ushort*)(ws + (size_t)(92u << 20));   // 128 MB bf16

  const int NW = 4096 * 1024;  // elements per weight matrix

  absmax_kernel<<<1024, 256, 0, stream>>>(w1, NW / 4, wmax + 0);
  absmax_kernel<<<1024, 256, 0, stream>>>(w2, NW / 4, wmax + 1);
  scales_kernel<<<1, 1, 0, stream>>>(wmax, bits, scal);
  wquant_kernel<<<NW / 1024, 256, 0, stream>>>(w1, scal, 0, w1q);
  wquant_kernel<<<NW / 1024, 256, 0, stream>>>(w2, scal, 1, w2q);
  ln_quant_kernel<<<16384, 256, 0, stream>>>(x, gamma, beta, xq, xscale);
  gemm1_kernel<<<dim3(4096 / BN, 16384 / BM), 256, 0, stream>>>(xq, w1q, xscale, scal, b1, h);
  hquant_kernel<<<16384, 256, 0, stream>>>(h, hq, hscale);
  gemm2_kernel<<<dim3(1024 / BN, 16384 / BM), 256, 0, stream>>>(hq, w2q, hscale, scal, b2, x,
                                                                mask, out);
}

// Round 4
// 438.994 us; speedup vs baseline: 1.0811x; 1.0053x over previous
//
#include <hip/hip_runtime.h>
#include <hip/hip_bf16.h>
#include <stdint.h>

// BitNet-style quantized FFN for MI355X (gfx950).
// Pipeline: absmax(w1,w2) -> scales -> wquant -> LN+actquant ->
//           i8 GEMM1 (+dequant+bias+swish, bf16 out) -> actquant(h) ->
//           i8 GEMM2 (+dequant+bias+mask+residual, fp32 out)
// R4: wave tile 64x128 (2x4 frags of 32x32x32) -> ds_read:MFMA ratio 0.75
//     (was 1.0); block tile 128x256 / 256x128; 48KB LDS; launch_bounds(256,2).
//     NB: SQ_LDS_BANK_CONFLICT == 8 cyc x staging-instr count (artifact of
//     global_load_lds write occupancy), not read conflicts.

typedef int v4i __attribute__((ext_vector_type(4)));
typedef int v16i __attribute__((ext_vector_type(16)));

#define BK 128   // bytes (=i8 elems) of K per tile

__device__ __forceinline__ float wave_max64(float v) {
#pragma unroll
  for (int off = 32; off; off >>= 1) v = fmaxf(v, __shfl_xor(v, off, 64));
  return v;
}

__device__ __forceinline__ void load16_to_lds(const int8_t* g, int8_t* l) {
  __builtin_amdgcn_global_load_lds((const __attribute__((address_space(1))) void*)g,
                                   (__attribute__((address_space(3))) void*)l, 16, 0, 0);
}

// ---------------- per-tensor weight absmax ----------------
__global__ __launch_bounds__(256) void absmax_kernel(const float* __restrict__ w, int n4,
                                                     int* __restrict__ slot) {
  float m = 0.f;
  const float4* w4 = (const float4*)w;
  for (int i = blockIdx.x * 256 + threadIdx.x; i < n4; i += gridDim.x * 256) {
    float4 v = w4[i];
    m = fmaxf(fmaxf(fabsf(v.x), fabsf(v.y)), fmaxf(fmaxf(fabsf(v.z), fabsf(v.w)), m));
  }
  m = wave_max64(m);
  __shared__ float sm[4];
  int lane = threadIdx.x & 63, wv = threadIdx.x >> 6;
  if (!lane) sm[wv] = m;
  __syncthreads();
  if (!threadIdx.x) {
    m = fmaxf(fmaxf(sm[0], sm[1]), fmaxf(sm[2], sm[3]));
    atomicMax(slot, __float_as_int(m));  // nonneg float bits are int-monotone
  }
}

// ---------------- scales ----------------
__global__ void scales_kernel(const int* __restrict__ wmax, const int* __restrict__ bits,
                              float* __restrict__ scal) {
  float qb = (float)((1 << (bits[0] - 1)) - 1);
  scal[2] = qb / fmaxf(__int_as_float(wmax[0]), 1e-5f);
  scal[3] = qb / fmaxf(__int_as_float(wmax[1]), 1e-5f);
  scal[4] = qb;
}

// ---------------- weight quantization to int8 ----------------
__global__ __launch_bounds__(256) void wquant_kernel(const float* __restrict__ w,
                                                     const float* __restrict__ scal, int which,
                                                     int8_t* __restrict__ out) {
  float s = scal[2 + which], qb = scal[4];
  int i = blockIdx.x * 256 + threadIdx.x;
  float4 v = ((const float4*)w)[i];
  char4 q;
  q.x = (char)(int)rintf(fminf(fmaxf(v.x * s, -qb), qb));
  q.y = (char)(int)rintf(fminf(fmaxf(v.y * s, -qb), qb));
  q.z = (char)(int)rintf(fminf(fmaxf(v.z * s, -qb), qb));
  q.w = (char)(int)rintf(fminf(fmaxf(v.w * s, -qb), qb));
  ((char4*)out)[i] = q;
}

// ---------------- fused LayerNorm + per-row int8 absmax quant ----------------
__global__ __launch_bounds__(256) void ln_quant_kernel(const float* __restrict__ x,
                                                       const float* __restrict__ gamma,
                                                       const float* __restrict__ beta,
                                                       int8_t* __restrict__ xq,
                                                       float* __restrict__ xscale) {
  const int row = blockIdx.x;            // 16384 rows, D=1024
  const int tid = threadIdx.x;           // 256 threads x 4 elems
  const float4 v = ((const float4*)(x + (size_t)row * 1024))[tid];
  float s = v.x + v.y + v.z + v.w;
  float ss = fmaf(v.x, v.x, fmaf(v.y, v.y, fmaf(v.z, v.z, v.w * v.w)));
#pragma unroll
  for (int off = 32; off; off >>= 1) {
    s += __shfl_xor(s, off, 64);
    ss += __shfl_xor(ss, off, 64);
  }
  __shared__ float sm[8];
  const int lane = tid & 63, wv = tid >> 6;
  if (!lane) { sm[wv] = s; sm[4 + wv] = ss; }
  __syncthreads();
  s = sm[0] + sm[1] + sm[2] + sm[3];
  ss = sm[4] + sm[5] + sm[6] + sm[7];
  const float mu = s * (1.f / 1024.f);
  const float var = ss * (1.f / 1024.f) - mu * mu;
  const float rstd = rsqrtf(var + 1e-5f);
  const float4 g = ((const float4*)gamma)[tid];
  const float4 bb = ((const float4*)beta)[tid];
  float y0 = (v.x - mu) * rstd * g.x + bb.x;
  float y1 = (v.y - mu) * rstd * g.y + bb.y;
  float y2 = (v.z - mu) * rstd * g.z + bb.z;
  float y3 = (v.w - mu) * rstd * g.w + bb.w;
  float am = fmaxf(fmaxf(fabsf(y0), fabsf(y1)), fmaxf(fabsf(y2), fabsf(y3)));
  am = wave_max64(am);
  __syncthreads();
  if (!lane) sm[wv] = am;
  __syncthreads();
  am = fmaxf(fmaxf(sm[0], sm[1]), fmaxf(sm[2], sm[3]));
  const float scale = 127.f / fmaxf(am, 1e-5f);
  char4 q;
  q.x = (char)(int)rintf(fminf(fmaxf(y0 * scale, -127.f), 127.f));
  q.y = (char)(int)rintf(fminf(fmaxf(y1 * scale, -127.f), 127.f));
  q.z = (char)(int)rintf(fminf(fmaxf(y2 * scale, -127.f), 127.f));
  q.w = (char)(int)rintf(fminf(fmaxf(y3 * scale, -127.f), 127.f));
  ((char4*)(xq + (size_t)row * 1024))[tid] = q;
  if (!tid) xscale[row] = scale;
}

// ---------------- per-row int8 absmax quant of bf16 h [16384,4096] ----------------
__global__ __launch_bounds__(256) void hquant_kernel(const ushort* __restrict__ h,
                                                     int8_t* __restrict__ hq,
                                                     float* __restrict__ hscale) {
  const int row = blockIdx.x;
  const int tid = threadIdx.x;           // 256 threads x 16 elems
  const int4* p = (const int4*)(h + (size_t)row * 4096);
  union { int4 i4; ushort u[8]; } ua, ub;
  ua.i4 = p[tid * 2];
  ub.i4 = p[tid * 2 + 1];
  float f[16];
#pragma unroll
  for (int i = 0; i < 8; ++i) f[i] = __uint_as_float((unsigned)ua.u[i] << 16);
#pragma unroll
  for (int i = 0; i < 8; ++i) f[8 + i] = __uint_as_float((unsigned)ub.u[i] << 16);
  float am = 0.f;
#pragma unroll
  for (int i = 0; i < 16; ++i) am = fmaxf(am, fabsf(f[i]));
  am = wave_max64(am);
  __shared__ float sm[4];
  const int lane = tid & 63, wv = tid >> 6;
  if (!lane) sm[wv] = am;
  __syncthreads();
  am = fmaxf(fmaxf(sm[0], sm[1]), fmaxf(sm[2], sm[3]));
  const float scale = 127.f / fmaxf(am, 1e-5f);
  union { int4 i4; char c[16]; } q;
#pragma unroll
  for (int i = 0; i < 16; ++i)
    q.c[i] = (char)(int)rintf(fminf(fmaxf(f[i] * scale, -127.f), 127.f));
  ((int4*)(hq + (size_t)row * 4096))[tid] = q.i4;
  if (!tid) hscale[row] = scale;
}

// ---------------- i8 MFMA GEMM core ----------------
// Block tile BMt x BNt, BK=128 B. 4 waves tiled 2x2, wave tile (BMt/2)x(BNt/2),
// per-wave frags AM x AN of 32x32x32 (AM=BMt/64, AN=BNt/64).
// LDS: 128-B rows, k-chunk s of row r stored at physical slot s^(r&7)
// (swizzle applied at global-fetch addressing; global_load_lds dest is
// wave-uniform base + lane*16).
template <int K, int BMt, int BNt>
__device__ __forceinline__ void gemm_core(const int8_t* __restrict__ A,
                                          const int8_t* __restrict__ B, int8_t* As, int8_t* Bs,
                                          v16i (&acc)[BMt / 64][BNt / 64]) {
  constexpr int AM = BMt / 64, AN = BNt / 64;
  const int tid = threadIdx.x;
  const int lane = tid & 63;
  const int wave = tid >> 6;
  const int wm = (wave & 1) * (BMt / 2);
  const int wn = (wave >> 1) * (BNt / 2);
  const int lrow = lane & 31;
  const int half = lane >> 5;
  const int x7 = lrow & 7;
  const size_t m0 = (size_t)blockIdx.y * BMt;
  const size_t n0 = (size_t)blockIdx.x * BNt;

  // staging: thread handles chunk (tid + t*256); row r = tid>>3 (+32 per t,
  // preserves r&7), swizzled k-offset cs
  const int r = tid >> 3;
  const int cs = ((tid & 7) ^ (r & 7)) << 4;
  const int8_t* ga = A + (m0 + r) * K + cs;
  const int8_t* gb = B + (n0 + r) * K + cs;
  int8_t* la = As + tid * 16;
  int8_t* lb = Bs + tid * 16;

  for (int k0 = 0; k0 < K; k0 += BK) {
    __syncthreads();
#pragma unroll
    for (int t = 0; t < BMt / 32; ++t)
      load16_to_lds(ga + (size_t)(t * 32) * K + k0, la + t * 4096);
#pragma unroll
    for (int t = 0; t < BNt / 32; ++t)
      load16_to_lds(gb + (size_t)(t * 32) * K + k0, lb + t * 4096);
    __syncthreads();
#pragma unroll
    for (int ks = 0; ks < 4; ++ks) {
      const int so = ((ks * 2 + half) ^ x7) << 4;
      v4i af[AM], bf[AN];
#pragma unroll
      for (int i = 0; i < AM; ++i)
        af[i] = *(const v4i*)(As + (wm + i * 32 + lrow) * 128 + so);
#pragma unroll
      for (int j = 0; j < AN; ++j)
        bf[j] = *(const v4i*)(Bs + (wn + j * 32 + lrow) * 128 + so);
#pragma unroll
      for (int i = 0; i < AM; ++i)
#pragma unroll
        for (int j = 0; j < AN; ++j)
          acc[i][j] = __builtin_amdgcn_mfma_i32_32x32x32_i8(af[i], bf[j], acc[i][j], 0, 0, 0);
    }
  }
}

// ---------------- GEMM1: C=xq@w1q^T, dequant+bias+swish -> bf16 h ----------------
// 128x256 tile: As 16KB, Bs 32KB
__global__ __launch_bounds__(256, 2) void gemm1_kernel(const int8_t* __restrict__ Aq,
                                                       const int8_t* __restrict__ Bq,
                                                       const float* __restrict__ xscale,
                                                       const float* __restrict__ scal,
                                                       const float* __restrict__ bias,
                                                       ushort* __restrict__ H) {
  __shared__ __align__(16) int8_t As[128 * 128];
  __shared__ __align__(16) int8_t Bs[256 * 128];
  v16i acc[2][4] = {};
  gemm_core<1024, 128, 256>(Aq, Bq, As, Bs, acc);
  const float sw1 = scal[2];
  const int lane = threadIdx.x & 63;
  const int wave = threadIdx.x >> 6;
  const int m0 = blockIdx.y * 128 + (wave & 1) * 64;
  const int n0 = blockIdx.x * 256 + (wave >> 1) * 128;
  const int cn = lane & 31;
  const int h4 = (lane >> 5) << 2;
#pragma unroll
  for (int i = 0; i < 2; ++i) {
#pragma unroll
    for (int reg = 0; reg < 16; ++reg) {
      const int row = (reg & 3) + ((reg >> 2) << 3) + h4;  // C/D layout (m74/m101)
      const int m = m0 + i * 32 + row;
      const float rcp = 1.0f / (xscale[m] * sw1);
#pragma unroll
      for (int j = 0; j < 4; ++j) {
        const int n = n0 + j * 32 + cn;
        const float v = (float)acc[i][j][reg] * rcp + bias[n];
        const float hsw = v / (1.0f + __expf(-v));  // swish
        __hip_bfloat16 hb = __float2bfloat16(hsw);
        H[(size_t)m * 4096 + n] = *(const ushort*)&hb;
      }
    }
  }
}

// ---------------- GEMM2: C=hq@w2q^T, dequant+bias+mask+residual -> fp32 out ----------------
// 256x128 tile: As 32KB, Bs 16KB
__global__ __launch_bounds__(256, 2) void gemm2_kernel(const int8_t* __restrict__ Aq,
                                                       const int8_t* __restrict__ Bq,
                                                       const float* __restrict__ hscale,
                                                       const float* __restrict__ scal,
                                                       const float* __restrict__ bias,
                                                       const float* __restrict__ x,
                                                       const float* __restrict__ mask,
                                                       float* __restrict__ out) {
  __shared__ __align__(16) int8_t As[256 * 128];
  __shared__ __align__(16) int8_t Bs[128 * 128];
  v16i acc[4][2] = {};
  gemm_core<4096, 256, 128>(Aq, Bq, As, Bs, acc);
  const float sw2 = scal[3];
  const int lane = threadIdx.x & 63;
  const int wave = threadIdx.x >> 6;
  const int m0 = blockIdx.y * 256 + (wave & 1) * 128;
  const int n0 = blockIdx.x * 128 + (wave >> 1) * 64;
  const int cn = lane & 31;
  const int h4 = (lane >> 5) << 2;
#pragma unroll
  for (int i = 0; i < 4; ++i) {
#pragma unroll
    for (int reg = 0; reg < 16; ++reg) {
      const int row = (reg & 3) + ((reg >> 2) << 3) + h4;
      const int m = m0 + i * 32 + row;
      const float rcp = 1.0f / (hscale[m] * sw2);
      const float mk = 0.5f * mask[m];
#pragma unroll
      for (int j = 0; j < 2; ++j) {
        const int n = n0 + j * 32 + cn;
        const float v = (float)acc[i][j][reg] * rcp + bias[n];
        const size_t idx = (size_t)m * 1024 + n;
        out[idx] = x[idx] + mk * v;
      }
    }
  }
}

extern "C" void kernel_launch(void* const* d_in, const int* in_sizes, int n_in, void* d_out,
                              int out_size, void* d_ws, size_t ws_size, hipStream_t stream) {
  const float* x = (const float*)d_in[0];      // [8,2048,1024]
  const float* mask = (const float*)d_in[1];   // [8,2048,1]
  const float* gamma = (const float*)d_in[2];  // [1024]
  const float* beta = (const float*)d_in[3];   // [1024]
  const float* w1 = (const float*)d_in[4];     // [4096,1024]
  const float* b1 = (const float*)d_in[5];     // [4096]
  const float* w2 = (const float*)d_in[6];     // [1024,4096]
  const float* b2 = (const float*)d_in[7];     // [1024]
  const int* bits = (const int*)d_in[8];       // scalar
  float* out = (float*)d_out;

  char* ws = (char*)d_ws;
  int* wmax = (int*)ws;                              // slots [0],[1]
  float* scal = (float*)ws;                          // [2]=sw1 [3]=sw2 [4]=qb
  float* xscale = (float*)(ws + (1u << 20));         // 16384 f32
  float* hscale = (float*)(ws + (2u << 20));         // 16384 f32
  int8_t* w1q = (int8_t*)(ws + (4u << 20));          // 4 MB
  int8_t* w2q = (int8_t*)(ws + (8u << 20));          // 4 MB
  int8_t* xq = (int8_t*)(ws + (12u << 20));          // 16 MB
  int8_t* hq = (int8_t*)(ws + (28u << 20));          // 64 MB
  ushort* h = (ushort*)(ws + (size_t)(92u << 20));   // 128 MB bf16

  const int NW = 4096 * 1024;  // elements per weight matrix

  absmax_kernel<<<1024, 256, 0, stream>>>(w1, NW / 4, wmax + 0);
  absmax_kernel<<<1024, 256, 0, stream>>>(w2, NW / 4, wmax + 1);
  scales_kernel<<<1, 1, 0, stream>>>(wmax, bits, scal);
  wquant_kernel<<<NW / 1024, 256, 0, stream>>>(w1, scal, 0, w1q);
  wquant_kernel<<<NW / 1024, 256, 0, stream>>>(w2, scal, 1, w2q);
  ln_quant_kernel<<<16384, 256, 0, stream>>>(x, gamma, beta, xq, xscale);
  gemm1_kernel<<<dim3(4096 / 256, 16384 / 128), 256, 0, stream>>>(xq, w1q, xscale, scal, b1, h);
  hquant_kernel<<<16384, 256, 0, stream>>>(h, hq, hscale);
  gemm2_kernel<<<dim3(1024 / 128, 16384 / 256), 256, 0, stream>>>(hq, w2q, hscale, scal, b2, x,
                                                                  mask, out);
}